// Round 6
// baseline (507.786 us; speedup 1.0000x reference)
//
#include <hip/hip_runtime.h>
#include <hip/hip_bf16.h>

#define BB  16
#define LL1 2048
#define LL2 2048
#define HH  768

typedef __attribute__((ext_vector_type(4))) float f32x4;
typedef __attribute__((ext_vector_type(8))) _Float16 f16x8;
typedef __attribute__((ext_vector_type(4))) _Float16 f16x4;

typedef __attribute__((address_space(3))) unsigned int lds_uint;
typedef __attribute__((address_space(1))) const unsigned int glob_uint;
__device__ __forceinline__ void gl_lds16(const void* g, void* l) {
  __builtin_amdgcn_global_load_lds((glob_uint*)g, (lds_uint*)l, 16, 0, 0);
}

// ---------------- fp32 -> fp16 plane ----------------
__global__ __launch_bounds__(256) void k_split16(
    const float* __restrict__ in, _Float16* __restrict__ p, int n4)
{
  int i = blockIdx.x * 256 + threadIdx.x;
  int stride = gridDim.x * 256;
  for (; i < n4; i += stride) {
    f32x4 v = ((const f32x4*)in)[i];
    f16x4 o;
#pragma unroll
    for (int q = 0; q < 4; ++q) o[q] = (_Float16)v[q];
    ((f16x4*)p)[i] = o;
  }
}

// ---------------- transpose wg -> fp16: Wt[n][k] = wg[k][n] ----------------
__global__ __launch_bounds__(256) void k_split_wt16(
    const float* __restrict__ wg, _Float16* __restrict__ wt)
{
  __shared__ float t[32][33];
  const int k0 = blockIdx.y * 32, n0 = blockIdx.x * 32;
  const int tx = threadIdx.x & 31, ty = threadIdx.x >> 5;  // ty 0..7
#pragma unroll
  for (int r = ty; r < 32; r += 8) t[r][tx] = wg[(size_t)(k0 + r) * HH + n0 + tx];
  __syncthreads();
#pragma unroll
  for (int r = ty; r < 32; r += 8)
    wt[(size_t)(n0 + r) * HH + k0 + tx] = (_Float16)t[tx][r];
}

// ---------------- K1: G = hi1 @ wg, fp16 MFMA, dbuf 2-phase ----------------
__global__ __launch_bounds__(256) void k_gemm_f16(
    const _Float16* __restrict__ A, const _Float16* __restrict__ Bt,
    _Float16* __restrict__ C)
{
  __shared__ _Float16 sA[2][128 * 32], sB[2][128 * 32];
  const int tid = threadIdx.x, lane = tid & 63, wave = tid >> 6;
  const int wm = (wave >> 1) * 64, wn = (wave & 1) * 64;
  const int m0 = blockIdx.y * 128, n0 = blockIdx.x * 128;
  const int fr = lane & 15, kg = (lane >> 4) * 8;
  const int rL = lane >> 2, cb = (lane & 3) * 8;
  const _Float16* pA = A  + (size_t)m0 * HH;
  const _Float16* pB = Bt + (size_t)n0 * HH;
  f32x4 acc[4][4] = {};

  const int base0 = wave * 1024, base1 = 4096 + wave * 1024;
  const size_t ro0 = (size_t)(wave * 16 + rL) * HH + cb;
  const size_t ro1 = (size_t)(64 + wave * 16 + rL) * HH + cb;

  gl_lds16(pA + ro0, (char*)&sA[0][0] + base0);
  gl_lds16(pA + ro1, (char*)&sA[0][0] + base1);
  gl_lds16(pB + ro0, (char*)&sB[0][0] + base0);
  gl_lds16(pB + ro1, (char*)&sB[0][0] + base1);
  __syncthreads();

  int cur = 0;
  for (int k0 = 0; k0 < HH; k0 += 32) {
    if (k0 + 32 < HH) {
      int nxt = cur ^ 1;
      gl_lds16(pA + ro0 + k0 + 32, (char*)&sA[nxt][0] + base0);
      gl_lds16(pA + ro1 + k0 + 32, (char*)&sA[nxt][0] + base1);
      gl_lds16(pB + ro0 + k0 + 32, (char*)&sB[nxt][0] + base0);
      gl_lds16(pB + ro1 + k0 + 32, (char*)&sB[nxt][0] + base1);
    }
    f16x8 fa[4], fb[4];
#pragma unroll
    for (int mi = 0; mi < 4; ++mi) fa[mi] = *(const f16x8*)&sA[cur][(wm + mi * 16 + fr) * 32 + kg];
#pragma unroll
    for (int ni = 0; ni < 4; ++ni) fb[ni] = *(const f16x8*)&sB[cur][(wn + ni * 16 + fr) * 32 + kg];
#pragma unroll
    for (int mi = 0; mi < 4; ++mi)
#pragma unroll
      for (int ni = 0; ni < 4; ++ni)
        acc[mi][ni] = __builtin_amdgcn_mfma_f32_16x16x32_f16(fa[mi], fb[ni], acc[mi][ni], 0, 0, 0);
    __syncthreads();
    cur ^= 1;
  }
#pragma unroll
  for (int mi = 0; mi < 4; ++mi)
#pragma unroll
    for (int ni = 0; ni < 4; ++ni)
#pragma unroll
      for (int j = 0; j < 4; ++j) {
        int row = m0 + wm + mi * 16 + (lane >> 4) * 4 + j;
        int col = n0 + wn + ni * 16 + fr;
        C[(size_t)row * HH + col] = (_Float16)acc[mi][ni][j];
      }
}

// ---------------- K2: S = G[b] @ hi2[b]^T, fp16 MFMA, dbuf 2-phase ----------------
// S out fp32 (fp16 S-storage was the R4 failure) + per-128-col-block rowmax Mx.
__global__ __launch_bounds__(256) void k_scores_f16(
    const _Float16* __restrict__ G, const _Float16* __restrict__ H2,
    float* __restrict__ S, float* __restrict__ Mx, int b_base)
{
  __shared__ _Float16 sA[2][128 * 32], sB[2][128 * 32];
  const int tid = threadIdx.x, lane = tid & 63, wave = tid >> 6;
  const int wm = (wave >> 1) * 64, wn = (wave & 1) * 64;
  const int z = blockIdx.z, b = b_base + z;
  const int i0 = blockIdx.y * 128, j0 = blockIdx.x * 128;
  const int fr = lane & 15, kg = (lane >> 4) * 8;
  const int rL = lane >> 2, cb = (lane & 3) * 8;
  const _Float16* pA = G  + (size_t)b * LL1 * HH + (size_t)i0 * HH;
  const _Float16* pB = H2 + (size_t)b * LL2 * HH + (size_t)j0 * HH;
  float* Sp = S + (size_t)z * LL1 * LL2;
  float* Mp = Mx + (size_t)z * LL1 * 16;
  f32x4 acc[4][4] = {};

  const int base0 = wave * 1024, base1 = 4096 + wave * 1024;
  const size_t ro0 = (size_t)(wave * 16 + rL) * HH + cb;
  const size_t ro1 = (size_t)(64 + wave * 16 + rL) * HH + cb;

  gl_lds16(pA + ro0, (char*)&sA[0][0] + base0);
  gl_lds16(pA + ro1, (char*)&sA[0][0] + base1);
  gl_lds16(pB + ro0, (char*)&sB[0][0] + base0);
  gl_lds16(pB + ro1, (char*)&sB[0][0] + base1);
  __syncthreads();

  int cur = 0;
  for (int k0 = 0; k0 < HH; k0 += 32) {
    if (k0 + 32 < HH) {
      int nxt = cur ^ 1;
      gl_lds16(pA + ro0 + k0 + 32, (char*)&sA[nxt][0] + base0);
      gl_lds16(pA + ro1 + k0 + 32, (char*)&sA[nxt][0] + base1);
      gl_lds16(pB + ro0 + k0 + 32, (char*)&sB[nxt][0] + base0);
      gl_lds16(pB + ro1 + k0 + 32, (char*)&sB[nxt][0] + base1);
    }
    f16x8 fa[4], fb[4];
#pragma unroll
    for (int mi = 0; mi < 4; ++mi) fa[mi] = *(const f16x8*)&sA[cur][(wm + mi * 16 + fr) * 32 + kg];
#pragma unroll
    for (int ni = 0; ni < 4; ++ni) fb[ni] = *(const f16x8*)&sB[cur][(wn + ni * 16 + fr) * 32 + kg];
#pragma unroll
    for (int mi = 0; mi < 4; ++mi)
#pragma unroll
      for (int ni = 0; ni < 4; ++ni)
        acc[mi][ni] = __builtin_amdgcn_mfma_f32_16x16x32_f16(fa[mi], fb[ni], acc[mi][ni], 0, 0, 0);
    __syncthreads();
    cur ^= 1;
  }

  // S writes (exact fp32)
#pragma unroll
  for (int mi = 0; mi < 4; ++mi)
#pragma unroll
    for (int ni = 0; ni < 4; ++ni)
#pragma unroll
      for (int j = 0; j < 4; ++j) {
        int row = i0 + wm + mi * 16 + (lane >> 4) * 4 + j;
        int col = j0 + wn + ni * 16 + fr;
        Sp[(size_t)row * LL2 + col] = acc[mi][ni][j];
      }

  // per-row blockmax over this 128x128 tile -> Mp[row][j0/128]
  float* smax = (float*)&sA[0][0];   // LDS reuse (K-loop done)
#pragma unroll
  for (int mi = 0; mi < 4; ++mi)
#pragma unroll
    for (int j = 0; j < 4; ++j) {
      float rm = fmaxf(fmaxf(acc[mi][0][j], acc[mi][1][j]),
                       fmaxf(acc[mi][2][j], acc[mi][3][j]));
#pragma unroll
      for (int off = 8; off >= 1; off >>= 1) rm = fmaxf(rm, __shfl_xor(rm, off));
      if ((lane & 15) == 0)
        smax[(wm + mi * 16 + (lane >> 4) * 4 + j) * 2 + (wave & 1)] = rm;
    }
  __syncthreads();
  if (tid < 128)
    Mp[(size_t)(i0 + tid) * 16 + (j0 >> 7)] = fmaxf(smax[tid * 2], smax[tid * 2 + 1]);
}

// ---------------- K3: select-and-gather via blockmax skip (exact) ----------------
__global__ __launch_bounds__(256) void k_select(
    const float* __restrict__ S, const float* __restrict__ Mx,
    const float* __restrict__ HI2, float* __restrict__ Out, int b_base)
{
  const int tid = threadIdx.x, lane = tid & 63, wv = tid >> 6;
  const int z = blockIdx.y, b = b_base + z;
  const int row = blockIdx.x * 4 + wv;
  const float* srow = S + ((size_t)z * LL1 + row) * LL2;
  const float* V = HI2 + (size_t)b * LL2 * HH;

  float bmax = Mx[((size_t)z * LL1 + row) * 16 + (lane & 15)];
  float m = bmax;
#pragma unroll
  for (int off = 8; off >= 1; off >>= 1) m = fmaxf(m, __shfl_xor(m, off));

  const float thr = m - 20.0f;
  float acc[12] = {};
  float lsum = 0.f;

  for (int jb = 0; jb < 16; ++jb) {
    float bj = __shfl(bmax, jb);
    if (bj <= thr) continue;   // no entry in this 128-block can be a hit (exact)
#pragma unroll
    for (int h = 0; h < 2; ++h) {
      float sval = srow[jb * 128 + h * 64 + lane];
      bool hit = sval > thr;
      unsigned long long mask = __ballot(hit);
      float p = hit ? __expf(sval - m) : 0.f;
      lsum += p;
      while (mask) {
        int src = __ffsll((long long)mask) - 1;
        mask &= mask - 1;
        float w = __shfl(p, src);
        int j = jb * 128 + h * 64 + src;
        const float* vr = V + (size_t)j * HH;
#pragma unroll
        for (int c = 0; c < 12; ++c) acc[c] = fmaf(w, vr[lane + 64 * c], acc[c]);
      }
    }
  }
#pragma unroll
  for (int off = 32; off >= 1; off >>= 1) lsum += __shfl_xor(lsum, off);
  const float inv = 1.0f / lsum;
  float* orow = Out + ((size_t)b * LL1 + row) * HH;
#pragma unroll
  for (int c = 0; c < 12; ++c) orow[lane + 64 * c] = acc[c] * inv;
}

extern "C" void kernel_launch(void* const* d_in, const int* in_sizes, int n_in,
                              void* d_out, int out_size, void* d_ws, size_t ws_size,
                              hipStream_t stream) {
  const float* hi1 = (const float*)d_in[0];
  const float* hi2 = (const float*)d_in[1];
  const float* wg  = (const float*)d_in[2];
  float* out = (float*)d_out;

  char* ws = (char*)d_ws;
  const size_t plane_elems = (size_t)BB * LL1 * HH;   // 25.17M
  const size_t plane_b = plane_elems * 2;             // 50.33MB (fp16)
  const size_t wt_b = (size_t)HH * HH * 2;            // 1.18MB
  const size_t s_per_b = (size_t)LL1 * LL2 * 4;       // 16.78MB (fp32 S)
  const size_t m_per_b = (size_t)LL1 * 16 * 4;        // 128KB (blockmax)

  _Float16* H2f = (_Float16*)ws;
  _Float16* Gf  = (_Float16*)(ws + plane_b);
  _Float16* Wtf = (_Float16*)(ws + 2 * plane_b);
  char* X = ws + 2 * plane_b + wt_b;                  // aliased: H1f then S/M
  _Float16* H1f = (_Float16*)X;

  const size_t fixed = 2 * plane_b + wt_b;
  int CB = 1;
  const int cand[5] = {16, 8, 4, 2, 1};
  for (int i = 0; i < 5; ++i) {
    size_t xneed = (size_t)cand[i] * (s_per_b + m_per_b);
    if (xneed < plane_b) xneed = plane_b;             // X also holds H1 plane
    if (fixed + xneed + 1024 <= ws_size) { CB = cand[i]; break; }
  }
  float* Sbuf = (float*)X;
  float* Mbuf = (float*)(X + (size_t)CB * s_per_b);

  k_split16<<<4096, 256, 0, stream>>>(hi1, H1f, (int)(plane_elems / 4));
  k_split16<<<4096, 256, 0, stream>>>(hi2, H2f, (int)(plane_elems / 4));
  k_split_wt16<<<dim3(HH / 32, HH / 32), 256, 0, stream>>>(wg, Wtf);

  k_gemm_f16<<<dim3(HH / 128, (BB * LL1) / 128), 256, 0, stream>>>(H1f, Wtf, Gf);

  for (int b0 = 0; b0 < BB; b0 += CB) {
    k_scores_f16<<<dim3(LL2 / 128, LL1 / 128, CB), 256, 0, stream>>>(Gf, H2f, Sbuf, Mbuf, b0);
    k_select<<<dim3(LL1 / 4, CB), 256, 0, stream>>>(Sbuf, Mbuf, hi2, out, b0);
  }
}

// Round 7
// 487.869 us; speedup vs baseline: 1.0408x; 1.0408x over previous
//
#include <hip/hip_runtime.h>
#include <hip/hip_bf16.h>

#define BB  16
#define LL1 2048
#define LL2 2048
#define HH  768

typedef __attribute__((ext_vector_type(4))) float f32x4;
typedef __attribute__((ext_vector_type(8))) _Float16 f16x8;
typedef __attribute__((ext_vector_type(4))) _Float16 f16x4;

typedef __attribute__((address_space(3))) unsigned int lds_uint;
typedef __attribute__((address_space(1))) const unsigned int glob_uint;
__device__ __forceinline__ void gl_lds16(const void* g, void* l) {
  __builtin_amdgcn_global_load_lds((glob_uint*)g, (lds_uint*)l, 16, 0, 0);
}

// ---------------- fp32 -> fp16 plane ----------------
__global__ __launch_bounds__(256) void k_split16(
    const float* __restrict__ in, _Float16* __restrict__ p, int n4)
{
  int i = blockIdx.x * 256 + threadIdx.x;
  int stride = gridDim.x * 256;
  for (; i < n4; i += stride) {
    f32x4 v = ((const f32x4*)in)[i];
    f16x4 o;
#pragma unroll
    for (int q = 0; q < 4; ++q) o[q] = (_Float16)v[q];
    ((f16x4*)p)[i] = o;
  }
}

// ---------------- transpose wg -> fp16: Wt[n][k] = wg[k][n] ----------------
__global__ __launch_bounds__(256) void k_split_wt16(
    const float* __restrict__ wg, _Float16* __restrict__ wt)
{
  __shared__ float t[32][33];
  const int k0 = blockIdx.y * 32, n0 = blockIdx.x * 32;
  const int tx = threadIdx.x & 31, ty = threadIdx.x >> 5;  // ty 0..7
#pragma unroll
  for (int r = ty; r < 32; r += 8) t[r][tx] = wg[(size_t)(k0 + r) * HH + n0 + tx];
  __syncthreads();
#pragma unroll
  for (int r = ty; r < 32; r += 8)
    wt[(size_t)(n0 + r) * HH + k0 + tx] = (_Float16)t[tx][r];
}

// Staging geometry, BK=64, 128-row tile, row stride 128B in LDS.
// XOR swizzle (G4/m173): LDS holds tile[row][bir ^ ((row&7)<<4)] at linear
// byte (row*128+bir); achieved by pre-swizzling the GLOBAL source column.
// ds_read applies the same XOR. Banks: 8 slots x 2 lanes -> conflict-free.

// ---------------- K1: G = hi1 @ wg, fp16 MFMA, BK=64 single-buf ----------------
__global__ __launch_bounds__(256) void k_gemm_f16(
    const _Float16* __restrict__ A, const _Float16* __restrict__ Bt,
    _Float16* __restrict__ C)
{
  __shared__ _Float16 sA[128 * 64], sB[128 * 64];
  const int tid = threadIdx.x, lane = tid & 63, wave = tid >> 6;
  const int wm = (wave >> 1) * 64, wn = (wave & 1) * 64;
  const int m0 = blockIdx.y * 128, n0 = blockIdx.x * 128;
  const int fr = lane & 15, kg = (lane >> 4) * 8;
  const _Float16* pA = A  + (size_t)m0 * HH;
  const _Float16* pB = Bt + (size_t)n0 * HH;
  f32x4 acc[4][4] = {};

  // staging: inst e, flat = e*256+tid; row=flat>>3; swizzled col
  size_t go[4]; int lo[4];
#pragma unroll
  for (int e = 0; e < 4; ++e) {
    int flat = e * 256 + tid;
    int row = flat >> 3;
    int col = ((flat & 7) * 8) ^ ((row & 7) << 3);  // fp16 units
    go[e] = (size_t)row * HH + col;
    lo[e] = flat * 16;                               // LDS bytes, linear
  }

  for (int k0 = 0; k0 < HH; k0 += 64) {
    __syncthreads();
    gl_lds16(pA + go[0] + k0, (char*)sA + lo[0]);
    gl_lds16(pA + go[1] + k0, (char*)sA + lo[1]);
    gl_lds16(pA + go[2] + k0, (char*)sA + lo[2]);
    gl_lds16(pA + go[3] + k0, (char*)sA + lo[3]);
    gl_lds16(pB + go[0] + k0, (char*)sB + lo[0]);
    gl_lds16(pB + go[1] + k0, (char*)sB + lo[1]);
    gl_lds16(pB + go[2] + k0, (char*)sB + lo[2]);
    gl_lds16(pB + go[3] + k0, (char*)sB + lo[3]);
    __syncthreads();
#pragma unroll
    for (int kk = 0; kk < 2; ++kk) {
      f16x8 fa[4], fb[4];
#pragma unroll
      for (int mi = 0; mi < 4; ++mi) {
        int r = wm + mi * 16 + fr;
        int kb = (kk * 64 + kg * 2) ^ ((r & 7) << 4);
        fa[mi] = *(const f16x8*)((const char*)sA + r * 128 + kb);
      }
#pragma unroll
      for (int ni = 0; ni < 4; ++ni) {
        int r = wn + ni * 16 + fr;
        int kb = (kk * 64 + kg * 2) ^ ((r & 7) << 4);
        fb[ni] = *(const f16x8*)((const char*)sB + r * 128 + kb);
      }
#pragma unroll
      for (int mi = 0; mi < 4; ++mi)
#pragma unroll
        for (int ni = 0; ni < 4; ++ni)
          acc[mi][ni] = __builtin_amdgcn_mfma_f32_16x16x32_f16(fa[mi], fb[ni], acc[mi][ni], 0, 0, 0);
    }
  }
#pragma unroll
  for (int mi = 0; mi < 4; ++mi)
#pragma unroll
    for (int ni = 0; ni < 4; ++ni)
#pragma unroll
      for (int j = 0; j < 4; ++j) {
        int row = m0 + wm + mi * 16 + (lane >> 4) * 4 + j;
        int col = n0 + wn + ni * 16 + fr;
        C[(size_t)row * HH + col] = (_Float16)acc[mi][ni][j];
      }
}

// ---------------- K2: S = G[b] @ hi2[b]^T, fp16 MFMA, BK=64 single-buf ----------------
// S out fp32 (fp16 S-storage was the R4 failure) + per-128-col-block rowmax Mx.
__global__ __launch_bounds__(256) void k_scores_f16(
    const _Float16* __restrict__ G, const _Float16* __restrict__ H2,
    float* __restrict__ S, float* __restrict__ Mx, int b_base)
{
  __shared__ _Float16 sA[128 * 64], sB[128 * 64];
  const int tid = threadIdx.x, lane = tid & 63, wave = tid >> 6;
  const int wm = (wave >> 1) * 64, wn = (wave & 1) * 64;
  const int z = blockIdx.z, b = b_base + z;
  const int i0 = blockIdx.y * 128, j0 = blockIdx.x * 128;
  const int fr = lane & 15, kg = (lane >> 4) * 8;
  const _Float16* pA = G  + (size_t)b * LL1 * HH + (size_t)i0 * HH;
  const _Float16* pB = H2 + (size_t)b * LL2 * HH + (size_t)j0 * HH;
  float* Sp = S + (size_t)z * LL1 * LL2;
  float* Mp = Mx + (size_t)z * LL1 * 16;
  f32x4 acc[4][4] = {};

  size_t go[4]; int lo[4];
#pragma unroll
  for (int e = 0; e < 4; ++e) {
    int flat = e * 256 + tid;
    int row = flat >> 3;
    int col = ((flat & 7) * 8) ^ ((row & 7) << 3);
    go[e] = (size_t)row * HH + col;
    lo[e] = flat * 16;
  }

  for (int k0 = 0; k0 < HH; k0 += 64) {
    __syncthreads();
    gl_lds16(pA + go[0] + k0, (char*)sA + lo[0]);
    gl_lds16(pA + go[1] + k0, (char*)sA + lo[1]);
    gl_lds16(pA + go[2] + k0, (char*)sA + lo[2]);
    gl_lds16(pA + go[3] + k0, (char*)sA + lo[3]);
    gl_lds16(pB + go[0] + k0, (char*)sB + lo[0]);
    gl_lds16(pB + go[1] + k0, (char*)sB + lo[1]);
    gl_lds16(pB + go[2] + k0, (char*)sB + lo[2]);
    gl_lds16(pB + go[3] + k0, (char*)sB + lo[3]);
    __syncthreads();
#pragma unroll
    for (int kk = 0; kk < 2; ++kk) {
      f16x8 fa[4], fb[4];
#pragma unroll
      for (int mi = 0; mi < 4; ++mi) {
        int r = wm + mi * 16 + fr;
        int kb = (kk * 64 + kg * 2) ^ ((r & 7) << 4);
        fa[mi] = *(const f16x8*)((const char*)sA + r * 128 + kb);
      }
#pragma unroll
      for (int ni = 0; ni < 4; ++ni) {
        int r = wn + ni * 16 + fr;
        int kb = (kk * 64 + kg * 2) ^ ((r & 7) << 4);
        fb[ni] = *(const f16x8*)((const char*)sB + r * 128 + kb);
      }
#pragma unroll
      for (int mi = 0; mi < 4; ++mi)
#pragma unroll
        for (int ni = 0; ni < 4; ++ni)
          acc[mi][ni] = __builtin_amdgcn_mfma_f32_16x16x32_f16(fa[mi], fb[ni], acc[mi][ni], 0, 0, 0);
    }
  }

  // S writes (exact fp32)
#pragma unroll
  for (int mi = 0; mi < 4; ++mi)
#pragma unroll
    for (int ni = 0; ni < 4; ++ni)
#pragma unroll
      for (int j = 0; j < 4; ++j) {
        int row = i0 + wm + mi * 16 + (lane >> 4) * 4 + j;
        int col = j0 + wn + ni * 16 + fr;
        Sp[(size_t)row * LL2 + col] = acc[mi][ni][j];
      }

  // per-row blockmax over this 128x128 tile -> Mp[row][j0/128]
  __syncthreads();
  float* smax = (float*)sA;   // LDS reuse (K-loop done)
#pragma unroll
  for (int mi = 0; mi < 4; ++mi)
#pragma unroll
    for (int j = 0; j < 4; ++j) {
      float rm = fmaxf(fmaxf(acc[mi][0][j], acc[mi][1][j]),
                       fmaxf(acc[mi][2][j], acc[mi][3][j]));
#pragma unroll
      for (int off = 8; off >= 1; off >>= 1) rm = fmaxf(rm, __shfl_xor(rm, off));
      if ((lane & 15) == 0)
        smax[(wm + mi * 16 + (lane >> 4) * 4 + j) * 2 + (wave & 1)] = rm;
    }
  __syncthreads();
  if (tid < 128)
    Mp[(size_t)(i0 + tid) * 16 + (j0 >> 7)] = fmaxf(smax[tid * 2], smax[tid * 2 + 1]);
}

// ---------------- K3: select-and-gather, 2 waves per row ----------------
// Blockmax skip is exact. Each row handled by 2 waves; both scan (cheap,
// skip-gated), each gathers 6 of the 12 output chunks -> serial chain halved.
__global__ __launch_bounds__(512) void k_select(
    const float* __restrict__ S, const float* __restrict__ Mx,
    const float* __restrict__ HI2, float* __restrict__ Out, int b_base)
{
  const int tid = threadIdx.x, lane = tid & 63, wv = tid >> 6;
  const int z = blockIdx.y, b = b_base + z;
  const int row = blockIdx.x * 4 + (wv >> 1);
  const int half = wv & 1;
  const float* srow = S + ((size_t)z * LL1 + row) * LL2;
  const float* V = HI2 + (size_t)b * LL2 * HH;

  float bmax = Mx[((size_t)z * LL1 + row) * 16 + (lane & 15)];
  float m = bmax;
#pragma unroll
  for (int off = 8; off >= 1; off >>= 1) m = fmaxf(m, __shfl_xor(m, off));

  const float thr = m - 20.0f;
  float acc[6] = {};
  float lsum = 0.f;

  for (int jb = 0; jb < 16; ++jb) {
    float bj = __shfl(bmax, jb);
    if (bj <= thr) continue;   // no entry in this 128-block can be a hit (exact)
#pragma unroll
    for (int h = 0; h < 2; ++h) {
      float sval = srow[jb * 128 + h * 64 + lane];
      bool hit = sval > thr;
      unsigned long long mask = __ballot(hit);
      float p = hit ? __expf(sval - m) : 0.f;
      lsum += p;
      while (mask) {
        int src = __ffsll((long long)mask) - 1;
        mask &= mask - 1;
        float w = __shfl(p, src);
        int j = jb * 128 + h * 64 + src;
        const float* vr = V + (size_t)j * HH + half * 384;
#pragma unroll
        for (int c = 0; c < 6; ++c) acc[c] = fmaf(w, vr[lane + 64 * c], acc[c]);
      }
    }
  }
#pragma unroll
  for (int off = 32; off >= 1; off >>= 1) lsum += __shfl_xor(lsum, off);
  const float inv = 1.0f / lsum;
  float* orow = Out + ((size_t)b * LL1 + row) * HH + half * 384;
#pragma unroll
  for (int c = 0; c < 6; ++c) orow[lane + 64 * c] = acc[c] * inv;
}

extern "C" void kernel_launch(void* const* d_in, const int* in_sizes, int n_in,
                              void* d_out, int out_size, void* d_ws, size_t ws_size,
                              hipStream_t stream) {
  const float* hi1 = (const float*)d_in[0];
  const float* hi2 = (const float*)d_in[1];
  const float* wg  = (const float*)d_in[2];
  float* out = (float*)d_out;

  char* ws = (char*)d_ws;
  const size_t plane_elems = (size_t)BB * LL1 * HH;   // 25.17M
  const size_t plane_b = plane_elems * 2;             // 50.33MB (fp16)
  const size_t wt_b = (size_t)HH * HH * 2;            // 1.18MB
  const size_t s_per_b = (size_t)LL1 * LL2 * 4;       // 16.78MB (fp32 S)
  const size_t m_per_b = (size_t)LL1 * 16 * 4;        // 128KB (blockmax)

  _Float16* H2f = (_Float16*)ws;
  _Float16* Gf  = (_Float16*)(ws + plane_b);
  _Float16* Wtf = (_Float16*)(ws + 2 * plane_b);
  char* X = ws + 2 * plane_b + wt_b;                  // aliased: H1f then S/M
  _Float16* H1f = (_Float16*)X;

  const size_t fixed = 2 * plane_b + wt_b;
  int CB = 1;
  const int cand[5] = {16, 8, 4, 2, 1};
  for (int i = 0; i < 5; ++i) {
    size_t xneed = (size_t)cand[i] * (s_per_b + m_per_b);
    if (xneed < plane_b) xneed = plane_b;             // X also holds H1 plane
    if (fixed + xneed + 1024 <= ws_size) { CB = cand[i]; break; }
  }
  float* Sbuf = (float*)X;
  float* Mbuf = (float*)(X + (size_t)CB * s_per_b);

  k_split16<<<4096, 256, 0, stream>>>(hi1, H1f, (int)(plane_elems / 4));
  k_split16<<<4096, 256, 0, stream>>>(hi2, H2f, (int)(plane_elems / 4));
  k_split_wt16<<<dim3(HH / 32, HH / 32), 256, 0, stream>>>(wg, Wtf);

  k_gemm_f16<<<dim3(HH / 128, (BB * LL1) / 128), 256, 0, stream>>>(H1f, Wtf, Gf);

  for (int b0 = 0; b0 < BB; b0 += CB) {
    k_scores_f16<<<dim3(LL2 / 128, LL1 / 128, CB), 256, 0, stream>>>(Gf, H2f, Sbuf, Mbuf, b0);
    k_select<<<dim3(LL1 / 4, CB), 512, 0, stream>>>(Sbuf, Mbuf, hi2, out, b0);
  }
}

// Round 8
// 429.377 us; speedup vs baseline: 1.1826x; 1.1362x over previous
//
#include <hip/hip_runtime.h>
#include <hip/hip_bf16.h>

#define BB  16
#define LL1 2048
#define LL2 2048
#define HH  768

typedef __attribute__((ext_vector_type(4))) float f32x4;
typedef __attribute__((ext_vector_type(8))) _Float16 f16x8;
typedef __attribute__((ext_vector_type(4))) _Float16 f16x4;

typedef __attribute__((address_space(3))) unsigned int lds_uint;
typedef __attribute__((address_space(1))) const unsigned int glob_uint;
__device__ __forceinline__ void gl_lds16(const void* g, void* l) {
  __builtin_amdgcn_global_load_lds((glob_uint*)g, (lds_uint*)l, 16, 0, 0);
}

// ---------------- fp32 -> fp16 plane ----------------
__global__ __launch_bounds__(256) void k_split16(
    const float* __restrict__ in, _Float16* __restrict__ p, int n4)
{
  int i = blockIdx.x * 256 + threadIdx.x;
  int stride = gridDim.x * 256;
  for (; i < n4; i += stride) {
    f32x4 v = ((const f32x4*)in)[i];
    f16x4 o;
#pragma unroll
    for (int q = 0; q < 4; ++q) o[q] = (_Float16)v[q];
    ((f16x4*)p)[i] = o;
  }
}

// ---------------- transpose wg -> fp16: Wt[n][k] = wg[k][n] ----------------
__global__ __launch_bounds__(256) void k_split_wt16(
    const float* __restrict__ wg, _Float16* __restrict__ wt)
{
  __shared__ float t[32][33];
  const int k0 = blockIdx.y * 32, n0 = blockIdx.x * 32;
  const int tx = threadIdx.x & 31, ty = threadIdx.x >> 5;
#pragma unroll
  for (int r = ty; r < 32; r += 8) t[r][tx] = wg[(size_t)(k0 + r) * HH + n0 + tx];
  __syncthreads();
#pragma unroll
  for (int r = ty; r < 32; r += 8)
    wt[(size_t)(n0 + r) * HH + k0 + tx] = (_Float16)t[tx][r];
}

// BK=32 double-buffered 2-phase K-loop. LDS row stride 64B, XOR swizzle
// (r&3)<<4 via pre-swizzled global source (gl_lds dest stays linear).
// Schedule per step: STAGE(next) || ds_read(cur)+MFMA ; vmcnt(0); s_barrier.

#define STAGE_PAIR(buf, koff)                                              \
  do {                                                                     \
    gl_lds16(pA + goA[0] + (koff), (char*)&sA[buf][0] + lo0);              \
    gl_lds16(pA + goA[1] + (koff), (char*)&sA[buf][0] + lo1);              \
    gl_lds16(pB + goB[0] + (koff), (char*)&sB[buf][0] + lo0);              \
    gl_lds16(pB + goB[1] + (koff), (char*)&sB[buf][0] + lo1);              \
  } while (0)

#define KLOOP_2PHASE(NT)                                                   \
  STAGE_PAIR(0, 0);                                                        \
  asm volatile("s_waitcnt vmcnt(0)" ::: "memory");                         \
  __builtin_amdgcn_s_barrier();                                            \
  __builtin_amdgcn_sched_barrier(0);                                       \
  for (int t = 0; t < (NT); ++t) {                                         \
    const int cur = t & 1;                                                 \
    if (t < (NT) - 1) STAGE_PAIR(cur ^ 1, (t + 1) * 32);                   \
    f16x8 fa[4], fb[4];                                                    \
    _Pragma("unroll")                                                      \
    for (int mi = 0; mi < 4; ++mi) {                                       \
      int r = wm + mi * 16 + fr;                                           \
      int kb = (kg * 2) ^ ((r & 3) << 4);                                  \
      fa[mi] = *(const f16x8*)((const char*)&sA[cur][0] + r * 64 + kb);    \
    }                                                                      \
    _Pragma("unroll")                                                      \
    for (int ni = 0; ni < 4; ++ni) {                                       \
      int r = wn + ni * 16 + fr;                                           \
      int kb = (kg * 2) ^ ((r & 3) << 4);                                  \
      fb[ni] = *(const f16x8*)((const char*)&sB[cur][0] + r * 64 + kb);    \
    }                                                                      \
    _Pragma("unroll")                                                      \
    for (int mi = 0; mi < 4; ++mi)                                         \
      _Pragma("unroll")                                                    \
      for (int ni = 0; ni < 4; ++ni)                                       \
        acc[mi][ni] = __builtin_amdgcn_mfma_f32_16x16x32_f16(              \
            fa[mi], fb[ni], acc[mi][ni], 0, 0, 0);                         \
    asm volatile("s_waitcnt vmcnt(0)" ::: "memory");                       \
    __builtin_amdgcn_s_barrier();                                          \
    __builtin_amdgcn_sched_barrier(0);                                     \
  }

// staging address setup (shared by both GEMMs): flat = e*256+tid in [0,512)
#define STAGE_ADDR_SETUP()                                                 \
  size_t goA[2], goB[2];                                                   \
  int lo0, lo1;                                                            \
  {                                                                        \
    int f0 = threadIdx.x, f1 = 256 + threadIdx.x;                          \
    int r0s = f0 >> 2, r1s = f1 >> 2;                                      \
    int c0 = ((f0 & 3) * 8) ^ ((r0s & 3) << 3);                            \
    int c1 = ((f1 & 3) * 8) ^ ((r1s & 3) << 3);                            \
    goA[0] = (size_t)r0s * HH + c0; goA[1] = (size_t)r1s * HH + c1;        \
    goB[0] = goA[0]; goB[1] = goA[1];                                      \
    lo0 = f0 * 16; lo1 = f1 * 16;                                          \
  }

// ---------------- K1: G = hi1 @ wg, fp16 MFMA, 2-phase dbuf ----------------
__global__ __launch_bounds__(256) void k_gemm_f16(
    const _Float16* __restrict__ A, const _Float16* __restrict__ Bt,
    _Float16* __restrict__ C)
{
  __shared__ _Float16 sA[2][4096], sB[2][4096];
  const int tid = threadIdx.x, lane = tid & 63, wave = tid >> 6;
  const int wm = (wave >> 1) * 64, wn = (wave & 1) * 64;
  const int m0 = blockIdx.y * 128, n0 = blockIdx.x * 128;
  const int fr = lane & 15, kg = (lane >> 4) * 8;
  const _Float16* pA = A  + (size_t)m0 * HH;
  const _Float16* pB = Bt + (size_t)n0 * HH;
  f32x4 acc[4][4] = {};
  STAGE_ADDR_SETUP();

  KLOOP_2PHASE(24);

#pragma unroll
  for (int mi = 0; mi < 4; ++mi)
#pragma unroll
    for (int ni = 0; ni < 4; ++ni)
#pragma unroll
      for (int j = 0; j < 4; ++j) {
        int row = m0 + wm + mi * 16 + (lane >> 4) * 4 + j;
        int col = n0 + wn + ni * 16 + fr;
        C[(size_t)row * HH + col] = (_Float16)acc[mi][ni][j];
      }
}

// ---------------- K2: S = G[b] @ hi2[b]^T ----------------
// S stored as fp16 diff from tile rowmax (reconstruct: Mx[tile] + diff);
// clamped at -28 (clamped entries provably can't be hits). Mx fp32 exact.
__global__ __launch_bounds__(256) void k_scores_f16(
    const _Float16* __restrict__ G, const _Float16* __restrict__ H2,
    _Float16* __restrict__ S16, float* __restrict__ Mx, int b_base)
{
  __shared__ _Float16 sA[2][4096], sB[2][4096];
  const int tid = threadIdx.x, lane = tid & 63, wave = tid >> 6;
  const int wm = (wave >> 1) * 64, wn = (wave & 1) * 64;
  const int z = blockIdx.z, b = b_base + z;
  const int i0 = blockIdx.y * 128, j0 = blockIdx.x * 128;
  const int fr = lane & 15, kg = (lane >> 4) * 8;
  const _Float16* pA = G  + (size_t)b * LL1 * HH + (size_t)i0 * HH;
  const _Float16* pB = H2 + (size_t)b * LL2 * HH + (size_t)j0 * HH;
  _Float16* Sp = S16 + (size_t)z * LL1 * LL2;
  float* Mp = Mx + (size_t)z * LL1 * 16;
  f32x4 acc[4][4] = {};
  STAGE_ADDR_SETUP();

  KLOOP_2PHASE(24);

  // blockmax per row of this 128x128 tile
  __syncthreads();
  float* smax = (float*)&sA[0][0];
#pragma unroll
  for (int mi = 0; mi < 4; ++mi)
#pragma unroll
    for (int j = 0; j < 4; ++j) {
      float rm = fmaxf(fmaxf(acc[mi][0][j], acc[mi][1][j]),
                       fmaxf(acc[mi][2][j], acc[mi][3][j]));
#pragma unroll
      for (int off = 8; off >= 1; off >>= 1) rm = fmaxf(rm, __shfl_xor(rm, off));
      if ((lane & 15) == 0)
        smax[(wm + mi * 16 + (lane >> 4) * 4 + j) * 2 + (wave & 1)] = rm;
    }
  __syncthreads();

  // write S as fp16 diffs from tile rowmax
#pragma unroll
  for (int mi = 0; mi < 4; ++mi)
#pragma unroll
    for (int j = 0; j < 4; ++j) {
      int rloc = wm + mi * 16 + (lane >> 4) * 4 + j;
      float tmax = fmaxf(smax[rloc * 2], smax[rloc * 2 + 1]);
      int row = i0 + rloc;
#pragma unroll
      for (int ni = 0; ni < 4; ++ni) {
        int col = j0 + wn + ni * 16 + fr;
        float d = fmaxf(acc[mi][ni][j] - tmax, -28.0f);
        Sp[(size_t)row * LL2 + col] = (_Float16)d;
      }
    }
  if (tid < 128)
    Mp[(size_t)(i0 + tid) * 16 + (j0 >> 7)] = fmaxf(smax[tid * 2], smax[tid * 2 + 1]);
}

// ---------------- K3: select-and-gather (fp16 diffs + fp16 V) ----------------
__global__ __launch_bounds__(512) void k_select(
    const _Float16* __restrict__ S16, const float* __restrict__ Mx,
    const _Float16* __restrict__ H2f, float* __restrict__ Out, int b_base)
{
  const int tid = threadIdx.x, lane = tid & 63, wv = tid >> 6;
  const int z = blockIdx.y, b = b_base + z;
  const int row = blockIdx.x * 4 + (wv >> 1);
  const int half = wv & 1;
  const _Float16* srow = S16 + ((size_t)z * LL1 + row) * LL2;
  const _Float16* V = H2f + (size_t)b * LL2 * HH;

  float bmax = Mx[((size_t)z * LL1 + row) * 16 + (lane & 15)];
  float m = bmax;
#pragma unroll
  for (int off = 8; off >= 1; off >>= 1) m = fmaxf(m, __shfl_xor(m, off));

  const float thr = m - 20.0f;
  float acc[6] = {};
  float lsum = 0.f;

  for (int jb = 0; jb < 16; ++jb) {
    float bj = __shfl(bmax, jb);
    if (bj <= thr) continue;   // exact skip: max of block below threshold
#pragma unroll
    for (int h = 0; h < 2; ++h) {
      float sval = bj + (float)srow[jb * 128 + h * 64 + lane];
      bool hit = sval > thr;
      unsigned long long mask = __ballot(hit);
      float p = hit ? __expf(sval - m) : 0.f;
      lsum += p;
      while (mask) {
        int src = __ffsll((long long)mask) - 1;
        mask &= mask - 1;
        float w = __shfl(p, src);
        int j = jb * 128 + h * 64 + src;
        const _Float16* vr = V + (size_t)j * HH + half * 384;
#pragma unroll
        for (int c = 0; c < 6; ++c) acc[c] = fmaf(w, (float)vr[lane + 64 * c], acc[c]);
      }
    }
  }
#pragma unroll
  for (int off = 32; off >= 1; off >>= 1) lsum += __shfl_xor(lsum, off);
  const float inv = 1.0f / lsum;
  float* orow = Out + ((size_t)b * LL1 + row) * HH + half * 384;
#pragma unroll
  for (int c = 0; c < 6; ++c) orow[lane + 64 * c] = acc[c] * inv;
}

extern "C" void kernel_launch(void* const* d_in, const int* in_sizes, int n_in,
                              void* d_out, int out_size, void* d_ws, size_t ws_size,
                              hipStream_t stream) {
  const float* hi1 = (const float*)d_in[0];
  const float* hi2 = (const float*)d_in[1];
  const float* wg  = (const float*)d_in[2];
  float* out = (float*)d_out;

  char* ws = (char*)d_ws;
  const size_t plane_elems = (size_t)BB * LL1 * HH;   // 25.17M
  const size_t plane_b = plane_elems * 2;             // 50.33MB (fp16)
  const size_t wt_b = (size_t)HH * HH * 2;            // 1.18MB
  const size_t s16_per_b = (size_t)LL1 * LL2 * 2;     // 8.39MB (fp16 S diffs)
  const size_t m_per_b = (size_t)LL1 * 16 * 4;        // 128KB (blockmax)

  _Float16* H2f = (_Float16*)ws;
  _Float16* Gf  = (_Float16*)(ws + plane_b);
  _Float16* Wtf = (_Float16*)(ws + 2 * plane_b);
  char* X = ws + 2 * plane_b + wt_b;                  // aliased: H1f then S16/Mx
  _Float16* H1f = (_Float16*)X;

  const size_t fixed = 2 * plane_b + wt_b;
  int CB = 1;
  const int cand[5] = {16, 8, 4, 2, 1};
  for (int i = 0; i < 5; ++i) {
    size_t xneed = (size_t)cand[i] * (s16_per_b + m_per_b);
    if (xneed < plane_b) xneed = plane_b;             // X also holds H1 plane
    if (fixed + xneed + 1024 <= ws_size) { CB = cand[i]; break; }
  }
  _Float16* S16 = (_Float16*)X;
  float* Mbuf = (float*)(X + (size_t)CB * s16_per_b);

  k_split16<<<4096, 256, 0, stream>>>(hi1, H1f, (int)(plane_elems / 4));
  k_split16<<<4096, 256, 0, stream>>>(hi2, H2f, (int)(plane_elems / 4));
  k_split_wt16<<<dim3(HH / 32, HH / 32), 256, 0, stream>>>(wg, Wtf);

  k_gemm_f16<<<dim3(HH / 128, (BB * LL1) / 128), 256, 0, stream>>>(H1f, Wtf, Gf);

  for (int b0 = 0; b0 < BB; b0 += CB) {
    k_scores_f16<<<dim3(LL2 / 128, LL1 / 128, CB), 256, 0, stream>>>(Gf, H2f, S16, Mbuf, b0);
    k_select<<<dim3(LL1 / 4, CB), 512, 0, stream>>>(S16, Mbuf, H2f, out, b0);
  }
}

// Round 9
// 400.416 us; speedup vs baseline: 1.2681x; 1.0723x over previous
//
#include <hip/hip_runtime.h>
#include <hip/hip_bf16.h>

#define BB  16
#define LL1 2048
#define LL2 2048
#define HH  768
#define NT  24   // 768 / 32

typedef __attribute__((ext_vector_type(4))) float f32x4;
typedef __attribute__((ext_vector_type(8))) _Float16 f16x8;
typedef __attribute__((ext_vector_type(4))) _Float16 f16x4;

typedef __attribute__((address_space(3))) unsigned int lds_uint;
typedef __attribute__((address_space(1))) const unsigned int glob_uint;
__device__ __forceinline__ void gl_lds16(const void* g, void* l) {
  __builtin_amdgcn_global_load_lds((glob_uint*)g, (lds_uint*)l, 16, 0, 0);
}

// ---------------- fp32 -> fp16 plane ----------------
__global__ __launch_bounds__(256) void k_split16(
    const float* __restrict__ in, _Float16* __restrict__ p, int n4)
{
  int i = blockIdx.x * 256 + threadIdx.x;
  int stride = gridDim.x * 256;
  for (; i < n4; i += stride) {
    f32x4 v = ((const f32x4*)in)[i];
    f16x4 o;
#pragma unroll
    for (int q = 0; q < 4; ++q) o[q] = (_Float16)v[q];
    ((f16x4*)p)[i] = o;
  }
}

// ---------------- transpose wg -> fp16: Wt[n][k] = wg[k][n] ----------------
__global__ __launch_bounds__(256) void k_split_wt16(
    const float* __restrict__ wg, _Float16* __restrict__ wt)
{
  __shared__ float t[32][33];
  const int k0 = blockIdx.y * 32, n0 = blockIdx.x * 32;
  const int tx = threadIdx.x & 31, ty = threadIdx.x >> 5;
#pragma unroll
  for (int r = ty; r < 32; r += 8) t[r][tx] = wg[(size_t)(k0 + r) * HH + n0 + tx];
  __syncthreads();
#pragma unroll
  for (int r = ty; r < 32; r += 8)
    wt[(size_t)(n0 + r) * HH + k0 + tx] = (_Float16)t[tx][r];
}

// ======== BM=256 x BN=128 x BK=32, 512 thr / 8 waves (4x2), 2-buffer ========
// LDS: A 2x16KB, B 2x8KB = 48KB static. Same R8-proven sync:
// STAGE(next) || ds_read+MFMA(cur) ; vmcnt(0) ; s_barrier.  Full K unroll so
// buffer indices and all addresses are compile-time.  XOR swizzle (r&3)<<4
// via pre-swizzled global source; ds_read applies the same XOR.

#define STAGE_SETUP()                                                      \
  size_t goA0, goA1, goB0; int loA0, loA1, loB0;                           \
  {                                                                        \
    int f0 = tid, f1 = 512 + tid;                                          \
    int r0 = f0 >> 2, s0 = f0 & 3, r1 = f1 >> 2, s1 = f1 & 3;              \
    goA0 = (size_t)r0 * HH + (size_t)((s0 ^ (r0 & 3)) * 8);                \
    goA1 = (size_t)r1 * HH + (size_t)((s1 ^ (r1 & 3)) * 8);                \
    loA0 = f0 * 16; loA1 = f1 * 16;                                        \
    int rb = tid >> 2, sb = tid & 3;                                       \
    goB0 = (size_t)rb * HH + (size_t)((sb ^ (rb & 3)) * 8);                \
    loB0 = tid * 16;                                                       \
  }                                                                        \
  int offA[4], offB[4];                                                    \
  _Pragma("unroll")                                                        \
  for (int mi = 0; mi < 4; ++mi) {                                         \
    int r = wm + mi * 16 + fr;                                             \
    offA[mi] = r * 64 + ((l4 * 16) ^ ((r & 3) << 4));                      \
  }                                                                        \
  _Pragma("unroll")                                                        \
  for (int ni = 0; ni < 4; ++ni) {                                         \
    int r = wn + ni * 16 + fr;                                             \
    offB[ni] = r * 64 + ((l4 * 16) ^ ((r & 3) << 4));                      \
  }

#define STG(buf, k0)                                                       \
  gl_lds16(pA + goA0 + (k0), (char*)&sA[buf][0] + loA0);                   \
  gl_lds16(pA + goA1 + (k0), (char*)&sA[buf][0] + loA1);                   \
  gl_lds16(pB + goB0 + (k0), (char*)&sB[buf][0] + loB0);

#define CMP(buf)                                                           \
  {                                                                        \
    f16x8 fa[4], fb[4];                                                    \
    _Pragma("unroll") for (int mi = 0; mi < 4; ++mi)                       \
      fa[mi] = *(const f16x8*)((const char*)&sA[buf][0] + offA[mi]);       \
    _Pragma("unroll") for (int ni = 0; ni < 4; ++ni)                       \
      fb[ni] = *(const f16x8*)((const char*)&sB[buf][0] + offB[ni]);       \
    _Pragma("unroll") for (int mi = 0; mi < 4; ++mi)                       \
      _Pragma("unroll") for (int ni = 0; ni < 4; ++ni)                     \
        acc[mi][ni] = __builtin_amdgcn_mfma_f32_16x16x32_f16(              \
            fa[mi], fb[ni], acc[mi][ni], 0, 0, 0);                         \
  }

#define KLOOP()                                                            \
  STG(0, 0);                                                               \
  asm volatile("s_waitcnt vmcnt(0)" ::: "memory");                         \
  __builtin_amdgcn_s_barrier();                                            \
  __builtin_amdgcn_sched_barrier(0);                                       \
  _Pragma("unroll")                                                        \
  for (int t = 0; t < NT; ++t) {                                           \
    if (t < NT - 1) { STG((t + 1) & 1, (t + 1) * 32); }                    \
    CMP(t & 1);                                                            \
    asm volatile("s_waitcnt vmcnt(0)" ::: "memory");                       \
    __builtin_amdgcn_s_barrier();                                          \
    __builtin_amdgcn_sched_barrier(0);                                     \
  }

// ---------------- K1: G = hi1 @ wg ----------------
__global__ __launch_bounds__(512, 4) void k_gemm_f16(
    const _Float16* __restrict__ A, const _Float16* __restrict__ Bt,
    _Float16* __restrict__ C)
{
  __shared__ _Float16 sA[2][256 * 32], sB[2][128 * 32];
  const int tid = threadIdx.x, lane = tid & 63, wave = tid >> 6;
  const int wm = (wave >> 1) * 64, wn = (wave & 1) * 64;
  const int m0 = blockIdx.y * 256, n0 = blockIdx.x * 128;
  const int fr = lane & 15, l4 = lane >> 4;
  const _Float16* pA = A  + (size_t)m0 * HH;
  const _Float16* pB = Bt + (size_t)n0 * HH;
  f32x4 acc[4][4] = {};
  STAGE_SETUP();
  KLOOP();

#pragma unroll
  for (int mi = 0; mi < 4; ++mi)
#pragma unroll
    for (int ni = 0; ni < 4; ++ni)
#pragma unroll
      for (int j = 0; j < 4; ++j) {
        int row = m0 + wm + mi * 16 + (lane >> 4) * 4 + j;
        int col = n0 + wn + ni * 16 + fr;
        C[(size_t)row * HH + col] = (_Float16)acc[mi][ni][j];
      }
}

// ---------------- K2: S = G[b] @ hi2[b]^T ----------------
// S stored as fp16 diff from tile rowmax (clamped -28); Mx fp32 exact.
__global__ __launch_bounds__(512, 4) void k_scores_f16(
    const _Float16* __restrict__ G, const _Float16* __restrict__ H2,
    _Float16* __restrict__ S16, float* __restrict__ Mx, int b_base)
{
  __shared__ _Float16 sA[2][256 * 32], sB[2][128 * 32];
  const int tid = threadIdx.x, lane = tid & 63, wave = tid >> 6;
  const int wm = (wave >> 1) * 64, wn = (wave & 1) * 64;
  const int z = blockIdx.z, b = b_base + z;
  const int i0 = blockIdx.y * 256, j0 = blockIdx.x * 128;
  const int fr = lane & 15, l4 = lane >> 4;
  const _Float16* pA = G  + (size_t)b * LL1 * HH + (size_t)i0 * HH;
  const _Float16* pB = H2 + (size_t)b * LL2 * HH + (size_t)j0 * HH;
  _Float16* Sp = S16 + (size_t)z * LL1 * LL2;
  float* Mp = Mx + (size_t)z * LL1 * 16;
  f32x4 acc[4][4] = {};
  STAGE_SETUP();
  KLOOP();

  // blockmax per row of this 256x128 tile
  __syncthreads();
  float* smax = (float*)&sA[0][0];   // 512 floats, LDS reuse
#pragma unroll
  for (int mi = 0; mi < 4; ++mi)
#pragma unroll
    for (int j = 0; j < 4; ++j) {
      float rm = fmaxf(fmaxf(acc[mi][0][j], acc[mi][1][j]),
                       fmaxf(acc[mi][2][j], acc[mi][3][j]));
#pragma unroll
      for (int off = 8; off >= 1; off >>= 1) rm = fmaxf(rm, __shfl_xor(rm, off));
      if ((lane & 15) == 0)
        smax[(wm + mi * 16 + (lane >> 4) * 4 + j) * 2 + (wave & 1)] = rm;
    }
  __syncthreads();

  // write S as fp16 diffs from tile rowmax
#pragma unroll
  for (int mi = 0; mi < 4; ++mi)
#pragma unroll
    for (int j = 0; j < 4; ++j) {
      int rloc = wm + mi * 16 + (lane >> 4) * 4 + j;
      float tmax = fmaxf(smax[rloc * 2], smax[rloc * 2 + 1]);
      int row = i0 + rloc;
#pragma unroll
      for (int ni = 0; ni < 4; ++ni) {
        int col = j0 + wn + ni * 16 + fr;
        float d = fmaxf(acc[mi][ni][j] - tmax, -28.0f);
        Sp[(size_t)row * LL2 + col] = (_Float16)d;
      }
    }
  if (tid < 256)
    Mp[(size_t)(i0 + tid) * 16 + (j0 >> 7)] = fmaxf(smax[tid * 2], smax[tid * 2 + 1]);
}

// ---------------- K3: select-and-gather (fp16 diffs + fp16 V) ----------------
__global__ __launch_bounds__(512) void k_select(
    const _Float16* __restrict__ S16, const float* __restrict__ Mx,
    const _Float16* __restrict__ H2f, float* __restrict__ Out, int b_base)
{
  const int tid = threadIdx.x, lane = tid & 63, wv = tid >> 6;
  const int z = blockIdx.y, b = b_base + z;
  const int row = blockIdx.x * 4 + (wv >> 1);
  const int half = wv & 1;
  const _Float16* srow = S16 + ((size_t)z * LL1 + row) * LL2;
  const _Float16* V = H2f + (size_t)b * LL2 * HH;

  float bmax = Mx[((size_t)z * LL1 + row) * 16 + (lane & 15)];
  float m = bmax;
#pragma unroll
  for (int off = 8; off >= 1; off >>= 1) m = fmaxf(m, __shfl_xor(m, off));

  const float thr = m - 20.0f;
  float acc[6] = {};
  float lsum = 0.f;

  for (int jb = 0; jb < 16; ++jb) {
    float bj = __shfl(bmax, jb);
    if (bj <= thr) continue;   // exact skip: max of block below threshold
#pragma unroll
    for (int h = 0; h < 2; ++h) {
      float sval = bj + (float)srow[jb * 128 + h * 64 + lane];
      bool hit = sval > thr;
      unsigned long long mask = __ballot(hit);
      float p = hit ? __expf(sval - m) : 0.f;
      lsum += p;
      while (mask) {
        int src = __ffsll((long long)mask) - 1;
        mask &= mask - 1;
        float w = __shfl(p, src);
        int j = jb * 128 + h * 64 + src;
        const _Float16* vr = V + (size_t)j * HH + half * 384;
#pragma unroll
        for (int c = 0; c < 6; ++c) acc[c] = fmaf(w, (float)vr[lane + 64 * c], acc[c]);
      }
    }
  }
#pragma unroll
  for (int off = 32; off >= 1; off >>= 1) lsum += __shfl_xor(lsum, off);
  const float inv = 1.0f / lsum;
  float* orow = Out + ((size_t)b * LL1 + row) * HH + half * 384;
#pragma unroll
  for (int c = 0; c < 6; ++c) orow[lane + 64 * c] = acc[c] * inv;
}

extern "C" void kernel_launch(void* const* d_in, const int* in_sizes, int n_in,
                              void* d_out, int out_size, void* d_ws, size_t ws_size,
                              hipStream_t stream) {
  const float* hi1 = (const float*)d_in[0];
  const float* hi2 = (const float*)d_in[1];
  const float* wg  = (const float*)d_in[2];
  float* out = (float*)d_out;

  char* ws = (char*)d_ws;
  const size_t plane_elems = (size_t)BB * LL1 * HH;   // 25.17M
  const size_t plane_b = plane_elems * 2;             // 50.33MB (fp16)
  const size_t wt_b = (size_t)HH * HH * 2;            // 1.18MB
  const size_t s16_per_b = (size_t)LL1 * LL2 * 2;     // 8.39MB (fp16 S diffs)
  const size_t m_per_b = (size_t)LL1 * 16 * 4;        // 128KB (blockmax)

  _Float16* H2f = (_Float16*)ws;
  _Float16* Gf  = (_Float16*)(ws + plane_b);
  _Float16* Wtf = (_Float16*)(ws + 2 * plane_b);
  char* X = ws + 2 * plane_b + wt_b;                  // aliased: H1f then S16/Mx
  _Float16* H1f = (_Float16*)X;

  const size_t fixed = 2 * plane_b + wt_b;
  int CB = 1;
  const int cand[5] = {16, 8, 4, 2, 1};
  for (int i = 0; i < 5; ++i) {
    size_t xneed = (size_t)cand[i] * (s16_per_b + m_per_b);
    if (xneed < plane_b) xneed = plane_b;             // X also holds H1 plane
    if (fixed + xneed + 1024 <= ws_size) { CB = cand[i]; break; }
  }
  _Float16* S16 = (_Float16*)X;
  float* Mbuf = (float*)(X + (size_t)CB * s16_per_b);

  k_split16<<<4096, 256, 0, stream>>>(hi1, H1f, (int)(plane_elems / 4));
  k_split16<<<4096, 256, 0, stream>>>(hi2, H2f, (int)(plane_elems / 4));
  k_split_wt16<<<dim3(HH / 32, HH / 32), 256, 0, stream>>>(wg, Wtf);

  k_gemm_f16<<<dim3(HH / 128, (BB * LL1) / 256), 512, 0, stream>>>(H1f, Wtf, Gf);

  for (int b0 = 0; b0 < BB; b0 += CB) {
    k_scores_f16<<<dim3(LL2 / 128, LL1 / 256, CB), 512, 0, stream>>>(Gf, H2f, S16, Mbuf, b0);
    k_select<<<dim3(LL1 / 4, CB), 512, 0, stream>>>(S16, Mbuf, H2f, out, b0);
  }
}

// Round 10
// 398.221 us; speedup vs baseline: 1.2751x; 1.0055x over previous
//
#include <hip/hip_runtime.h>
#include <hip/hip_bf16.h>

#define BB  16
#define LL1 2048
#define LL2 2048
#define HH  768
#define NKT 12   // 768 / 64

typedef __attribute__((ext_vector_type(4))) float f32x4;
typedef __attribute__((ext_vector_type(8))) _Float16 f16x8;
typedef __attribute__((ext_vector_type(4))) _Float16 f16x4;

typedef __attribute__((address_space(3))) unsigned int lds_uint;
typedef __attribute__((address_space(1))) const unsigned int glob_uint;
__device__ __forceinline__ void gl_lds16(const void* g, void* l) {
  __builtin_amdgcn_global_load_lds((glob_uint*)g, (lds_uint*)l, 16, 0, 0);
}

// ---------------- fp32 -> fp16 plane ----------------
__global__ __launch_bounds__(256) void k_split16(
    const float* __restrict__ in, _Float16* __restrict__ p, int n4)
{
  int i = blockIdx.x * 256 + threadIdx.x;
  int stride = gridDim.x * 256;
  for (; i < n4; i += stride) {
    f32x4 v = ((const f32x4*)in)[i];
    f16x4 o;
#pragma unroll
    for (int q = 0; q < 4; ++q) o[q] = (_Float16)v[q];
    ((f16x4*)p)[i] = o;
  }
}

// ---------------- transpose wg -> fp16: Wt[n][k] = wg[k][n] ----------------
__global__ __launch_bounds__(256) void k_split_wt16(
    const float* __restrict__ wg, _Float16* __restrict__ wt)
{
  __shared__ float t[32][33];
  const int k0 = blockIdx.y * 32, n0 = blockIdx.x * 32;
  const int tx = threadIdx.x & 31, ty = threadIdx.x >> 5;
#pragma unroll
  for (int r = ty; r < 32; r += 8) t[r][tx] = wg[(size_t)(k0 + r) * HH + n0 + tx];
  __syncthreads();
#pragma unroll
  for (int r = ty; r < 32; r += 8)
    wt[(size_t)(n0 + r) * HH + k0 + tx] = (_Float16)t[tx][r];
}

// ======== 256x256 tile, BK=64, 8 waves (2m x 4n), wave-tile 128x64 ========
// LDS: sA/sB [2 dbuf][2 kk-planes][256 rows][32 k] fp16 = 128 KB total.
// Counted-vmcnt pipeline (T3+T4): per K-tile 2 phases; each phase
// {12 ds_read ; stage (A,B) kk-plane of tile t+1 (4 gl_lds) ; 32 MFMA ;
//  vmcnt(4) ; s_barrier}. 8 loads stay in flight; never drained mid-loop.
// Swizzle: 64B rows, slot = s ^ ((r>>1)&3)  -> 2 lanes/bank, conflict-free.

#define STAGE_SETUP()                                                       \
  size_t gA0, gA1; int lA0, lA1;                                            \
  {                                                                         \
    int f0 = tid, f1 = 512 + tid;                                           \
    int r0 = f0 >> 2, s0 = f0 & 3, r1 = f1 >> 2, s1 = f1 & 3;               \
    gA0 = (size_t)r0 * HH + (size_t)((s0 ^ ((r0 >> 1) & 3)) * 8);           \
    gA1 = (size_t)r1 * HH + (size_t)((s1 ^ ((r1 >> 1) & 3)) * 8);           \
    lA0 = f0 * 16; lA1 = f1 * 16;                                           \
  }                                                                         \
  int offA[8], offB[4];                                                     \
  _Pragma("unroll")                                                         \
  for (int mi = 0; mi < 8; ++mi) {                                          \
    int r = wml + mi * 16 + fr;                                             \
    offA[mi] = r * 64 + ((l4 ^ ((r >> 1) & 3)) * 16);                       \
  }                                                                         \
  _Pragma("unroll")                                                         \
  for (int ni = 0; ni < 4; ++ni) {                                          \
    int r = wnl + ni * 16 + fr;                                             \
    offB[ni] = r * 64 + ((l4 ^ ((r >> 1) & 3)) * 16);                       \
  }

#define STG_A(db, kk, kt)                                                   \
  gl_lds16(pA + gA0 + (kt) * 64 + (kk) * 32, (char*)&sA[db][kk][0] + lA0);  \
  gl_lds16(pA + gA1 + (kt) * 64 + (kk) * 32, (char*)&sA[db][kk][0] + lA1);
#define STG_B(db, kk, kt)                                                   \
  gl_lds16(pB + gA0 + (kt) * 64 + (kk) * 32, (char*)&sB[db][kk][0] + lA0);  \
  gl_lds16(pB + gA1 + (kt) * 64 + (kk) * 32, (char*)&sB[db][kk][0] + lA1);

#define PHASE(kt, kk, DOSTG, VMC)                                           \
  {                                                                         \
    const int cur_ = (kt) & 1;                                              \
    f16x8 fa[8], fb[4];                                                     \
    _Pragma("unroll") for (int mi = 0; mi < 8; ++mi)                        \
      fa[mi] = *(const f16x8*)((const char*)&sA[cur_][kk][0] + offA[mi]);   \
    _Pragma("unroll") for (int ni = 0; ni < 4; ++ni)                        \
      fb[ni] = *(const f16x8*)((const char*)&sB[cur_][kk][0] + offB[ni]);   \
    if (DOSTG) {                                                            \
      STG_A(((kt) + 1) & 1, kk, (kt) + 1);                                  \
      STG_B(((kt) + 1) & 1, kk, (kt) + 1);                                  \
    }                                                                       \
    __builtin_amdgcn_s_setprio(1);                                          \
    _Pragma("unroll") for (int mi = 0; mi < 8; ++mi)                        \
      _Pragma("unroll") for (int ni = 0; ni < 4; ++ni)                      \
        acc[mi][ni] = __builtin_amdgcn_mfma_f32_16x16x32_f16(               \
            fa[mi], fb[ni], acc[mi][ni], 0, 0, 0);                          \
    __builtin_amdgcn_s_setprio(0);                                          \
    asm volatile("s_waitcnt vmcnt(" VMC ")" ::: "memory");                  \
    __builtin_amdgcn_s_barrier();                                           \
    __builtin_amdgcn_sched_barrier(0);                                      \
  }

#define KLOOP()                                                             \
  STG_A(0, 0, 0); STG_B(0, 0, 0);                                           \
  STG_A(0, 1, 0); STG_B(0, 1, 0);                                           \
  asm volatile("s_waitcnt vmcnt(4)" ::: "memory");                          \
  __builtin_amdgcn_s_barrier();                                             \
  __builtin_amdgcn_sched_barrier(0);                                        \
  _Pragma("unroll")                                                         \
  for (int t = 0; t < NKT - 1; ++t) {                                       \
    PHASE(t, 0, 1, "4");                                                    \
    PHASE(t, 1, 1, "4");                                                    \
  }                                                                         \
  PHASE(NKT - 1, 0, 0, "0");                                                \
  PHASE(NKT - 1, 1, 0, "0");

// ---------------- K1: G = hi1 @ wg ----------------
__global__ __launch_bounds__(512, 2) void k_gemm_f16(
    const _Float16* __restrict__ A, const _Float16* __restrict__ Bt,
    _Float16* __restrict__ C)
{
  __shared__ _Float16 sA[2][2][8192], sB[2][2][8192];   // 128 KB
  const int tid = threadIdx.x, lane = tid & 63, wave = tid >> 6;
  const int wml = (wave >> 2) * 128, wnl = (wave & 3) * 64;
  const int m0 = blockIdx.y * 256, n0 = blockIdx.x * 256;
  const int fr = lane & 15, l4 = lane >> 4;
  const _Float16* pA = A  + (size_t)m0 * HH;
  const _Float16* pB = Bt + (size_t)n0 * HH;
  f32x4 acc[8][4] = {};
  STAGE_SETUP();
  KLOOP();

#pragma unroll
  for (int mi = 0; mi < 8; ++mi)
#pragma unroll
    for (int ni = 0; ni < 4; ++ni)
#pragma unroll
      for (int j = 0; j < 4; ++j) {
        int row = m0 + wml + mi * 16 + l4 * 4 + j;
        int col = n0 + wnl + ni * 16 + fr;
        C[(size_t)row * HH + col] = (_Float16)acc[mi][ni][j];
      }
}

// ---------------- K2: S = G[b] @ hi2[b]^T ----------------
// S stored as fp16 diff from per-128-col-block rowmax (clamp -28); Mx fp32.
__global__ __launch_bounds__(512, 2) void k_scores_f16(
    const _Float16* __restrict__ G, const _Float16* __restrict__ H2,
    _Float16* __restrict__ S16, float* __restrict__ Mx, int b_base)
{
  __shared__ _Float16 sA[2][2][8192], sB[2][2][8192];   // 128 KB
  const int tid = threadIdx.x, lane = tid & 63, wave = tid >> 6;
  const int wml = (wave >> 2) * 128, wnl = (wave & 3) * 64;
  const int z = blockIdx.z, b = b_base + z;
  const int i0 = blockIdx.y * 256, j0 = blockIdx.x * 256;
  const int fr = lane & 15, l4 = lane >> 4;
  const _Float16* pA = G  + (size_t)b * LL1 * HH + (size_t)i0 * HH;
  const _Float16* pB = H2 + (size_t)b * LL2 * HH + (size_t)j0 * HH;
  _Float16* Sp = S16 + (size_t)z * LL1 * LL2;
  float* Mp = Mx + (size_t)z * LL1 * 16;
  f32x4 acc[8][4] = {};
  STAGE_SETUP();
  KLOOP();

  // per-row per-64-col wave max -> smax[256][4] (LDS reuse)
  __syncthreads();
  float* smax = (float*)&sA[0][0][0];
#pragma unroll
  for (int mi = 0; mi < 8; ++mi)
#pragma unroll
    for (int j = 0; j < 4; ++j) {
      float rm = fmaxf(fmaxf(acc[mi][0][j], acc[mi][1][j]),
                       fmaxf(acc[mi][2][j], acc[mi][3][j]));
#pragma unroll
      for (int off = 8; off >= 1; off >>= 1) rm = fmaxf(rm, __shfl_xor(rm, off));
      if (fr == 0)
        smax[(wml + mi * 16 + l4 * 4 + j) * 4 + (wave & 3)] = rm;
    }
  __syncthreads();

  // write S as fp16 diffs from the row's 128-block max
  const int hb = (wave & 3) >> 1;   // which 128-col half this wave is in
#pragma unroll
  for (int mi = 0; mi < 8; ++mi)
#pragma unroll
    for (int j = 0; j < 4; ++j) {
      int rloc = wml + mi * 16 + l4 * 4 + j;
      float tmax = fmaxf(smax[rloc * 4 + 2 * hb], smax[rloc * 4 + 2 * hb + 1]);
      int row = i0 + rloc;
#pragma unroll
      for (int ni = 0; ni < 4; ++ni) {
        int col = j0 + wnl + ni * 16 + fr;
        float d = fmaxf(acc[mi][ni][j] - tmax, -28.0f);
        Sp[(size_t)row * LL2 + col] = (_Float16)d;
      }
    }
  if (tid < 256) {
    float m0v = fmaxf(smax[tid * 4 + 0], smax[tid * 4 + 1]);
    float m1v = fmaxf(smax[tid * 4 + 2], smax[tid * 4 + 3]);
    Mp[(size_t)(i0 + tid) * 16 + (j0 >> 7)]     = m0v;
    Mp[(size_t)(i0 + tid) * 16 + (j0 >> 7) + 1] = m1v;
  }
}

// ---------------- K3: select-and-gather (fp16 diffs + fp16 V) ----------------
__global__ __launch_bounds__(512) void k_select(
    const _Float16* __restrict__ S16, const float* __restrict__ Mx,
    const _Float16* __restrict__ H2f, float* __restrict__ Out, int b_base)
{
  const int tid = threadIdx.x, lane = tid & 63, wv = tid >> 6;
  const int z = blockIdx.y, b = b_base + z;
  const int row = blockIdx.x * 4 + (wv >> 1);
  const int half = wv & 1;
  const _Float16* srow = S16 + ((size_t)z * LL1 + row) * LL2;
  const _Float16* V = H2f + (size_t)b * LL2 * HH;

  float bmax = Mx[((size_t)z * LL1 + row) * 16 + (lane & 15)];
  float m = bmax;
#pragma unroll
  for (int off = 8; off >= 1; off >>= 1) m = fmaxf(m, __shfl_xor(m, off));

  const float thr = m - 20.0f;
  float acc[6] = {};
  float lsum = 0.f;

  for (int jb = 0; jb < 16; ++jb) {
    float bj = __shfl(bmax, jb);
    if (bj <= thr) continue;   // exact skip: max of block below threshold
#pragma unroll
    for (int h = 0; h < 2; ++h) {
      float sval = bj + (float)srow[jb * 128 + h * 64 + lane];
      bool hit = sval > thr;
      unsigned long long mask = __ballot(hit);
      float p = hit ? __expf(sval - m) : 0.f;
      lsum += p;
      while (mask) {
        int src = __ffsll((long long)mask) - 1;
        mask &= mask - 1;
        float w = __shfl(p, src);
        int j = jb * 128 + h * 64 + src;
        const _Float16* vr = V + (size_t)j * HH + half * 384;
#pragma unroll
        for (int c = 0; c < 6; ++c) acc[c] = fmaf(w, (float)vr[lane + 64 * c], acc[c]);
      }
    }
  }
#pragma unroll
  for (int off = 32; off >= 1; off >>= 1) lsum += __shfl_xor(lsum, off);
  const float inv = 1.0f / lsum;
  float* orow = Out + ((size_t)b * LL1 + row) * HH + half * 384;
#pragma unroll
  for (int c = 0; c < 6; ++c) orow[lane + 64 * c] = acc[c] * inv;
}

extern "C" void kernel_launch(void* const* d_in, const int* in_sizes, int n_in,
                              void* d_out, int out_size, void* d_ws, size_t ws_size,
                              hipStream_t stream) {
  const float* hi1 = (const float*)d_in[0];
  const float* hi2 = (const float*)d_in[1];
  const float* wg  = (const float*)d_in[2];
  float* out = (float*)d_out;

  char* ws = (char*)d_ws;
  const size_t plane_elems = (size_t)BB * LL1 * HH;   // 25.17M
  const size_t plane_b = plane_elems * 2;             // 50.33MB (fp16)
  const size_t wt_b = (size_t)HH * HH * 2;            // 1.18MB
  const size_t s16_per_b = (size_t)LL1 * LL2 * 2;     // 8.39MB (fp16 S diffs)
  const size_t m_per_b = (size_t)LL1 * 16 * 4;        // 128KB (blockmax)

  _Float16* H2f = (_Float16*)ws;
  _Float16* Gf  = (_Float16*)(ws + plane_b);
  _Float16* Wtf = (_Float16*)(ws + 2 * plane_b);
  char* X = ws + 2 * plane_b + wt_b;                  // aliased: H1f then S16/Mx
  _Float16* H1f = (_Float16*)X;

  const size_t fixed = 2 * plane_b + wt_b;
  int CB = 1;
  const int cand[5] = {16, 8, 4, 2, 1};
  for (int i = 0; i < 5; ++i) {
    size_t xneed = (size_t)cand[i] * (s16_per_b + m_per_b);
    if (xneed < plane_b) xneed = plane_b;             // X also holds H1 plane
    if (fixed + xneed + 1024 <= ws_size) { CB = cand[i]; break; }
  }
  _Float16* S16 = (_Float16*)X;
  float* Mbuf = (float*)(X + (size_t)CB * s16_per_b);

  k_split16<<<4096, 256, 0, stream>>>(hi1, H1f, (int)(plane_elems / 4));
  k_split16<<<4096, 256, 0, stream>>>(hi2, H2f, (int)(plane_elems / 4));
  k_split_wt16<<<dim3(HH / 32, HH / 32), 256, 0, stream>>>(wg, Wtf);

  k_gemm_f16<<<dim3(HH / 256, (BB * LL1) / 256), 512, 0, stream>>>(H1f, Wtf, Gf);

  for (int b0 = 0; b0 < BB; b0 += CB) {
    k_scores_f16<<<dim3(LL2 / 256, LL1 / 256, CB), 512, 0, stream>>>(Gf, H2f, S16, Mbuf, b0);
    k_select<<<dim3(LL1 / 4, CB), 512, 0, stream>>>(S16, Mbuf, H2f, out, b0);
  }
}